// Round 15
// baseline (32.609 us; speedup 1.0000x reference)
//
#include <hip/hip_runtime.h>
#include <math.h>

#define NPTS_C 100
#define EPS_C 1e-8

#if defined(__has_builtin)
# if __has_builtin(__builtin_amdgcn_exp2f)
#  define FAST_EXP2(x) __builtin_amdgcn_exp2f(x)
#  define FAST_LOG2(x) __builtin_amdgcn_logf(x)
# else
#  define FAST_EXP2(x) exp2f(x)
#  define FAST_LOG2(x) log2f(x)
# endif
#else
# define FAST_EXP2(x) exp2f(x)
# define FAST_LOG2(x) log2f(x)
#endif

#define LOG2E_F 1.44269504088896340736f
#define LN2_F   0.69314718055994530942f

__device__ __forceinline__ float dot4(float4 a, float4 b) {
    return a.x * b.x + a.y * b.y + a.z * b.z + a.w * b.w;
}

__device__ __forceinline__ float wave_reduce_sum(float v) {
#pragma unroll
    for (int m = 1; m < 64; m <<= 1)
        v += __shfl_xor(v, m, 64);
    return v;
}

// ---------------- fast path constants (C=512, K=10, NPTS=100) --------------
constexpr int KC   = 10;
constexpr int NTAB = 550;   // sum_{i=1..10} 10*i

// Block = 256 threads = 4 waves; each wave owns 16 rows = 4 GROUPS of 4,
// software-pipelined with a single 8-float4 buffer (32 VGPR):
//   load(g) -> dots(g) -> issue load(g+1) -> quad(g) -> dots(g+1) -> ...
// so ~8KB of next-group loads is in flight under every quad phase (the
// formerly memory-silent 40% of wave time). Contiguous-load layout (R14):
// each load instr reads 64 consecutive float4 = 1KB contiguous.
// Dot reduce: xor1/2/4 (8-lane group sums) -> select row by lane&3 ->
// xor8/16/32 (cross-group) => row r's (da,db) in every lane with lane&3==r.
// Quad: 16 lanes/row (part = lane>>2), ~34 pts/lane, reduce xor4/8/16/32.
// Grid = B/64 = 1024 blocks = exactly 4 resident blocks/CU (no churn).
__global__ __launch_bounds__(256, 4) void fused512_kernel(
    const float* __restrict__ x, const float* __restrict__ Wa,
    const float* __restrict__ ba, const float* __restrict__ Wb,
    const float* __restrict__ bb, float* __restrict__ out)
{
    __shared__ __align__(16) float2 s_tab[NTAB];   // (log2 g, log2(1-g)), fp32 grid

    const int tid = threadIdx.x;

    // row-invariant log2 tables (fp32 grid, matches ref; last point of last
    // segment rounds to 1.0f -> log2f(0) = -inf -> exp2 -> 0)
    {
        int base = 0;
#pragma unroll
        for (int i = 1; i <= KC; ++i) {
            const int n = 10 * i;
            const double start = EPS_C;
            const double stop  = (double)i / (double)KC - EPS_C;
            const double step  = (stop - start) / (double)(n - 1);
            for (int j = tid; j < n; j += 256) {
                const double g = (j == n - 1) ? stop : start + step * (double)j;
                const float g32 = (float)g;
                s_tab[base + j] = make_float2(log2f(g32), log2f(1.0f - g32));
            }
            base += n;
        }
    }
    __syncthreads();

    const int lane = tid & 63;
    const int wv   = tid >> 6;
    const int r4   = lane & 3;    // which of the group's 4 rows
    const int part = lane >> 2;   // 0..15: this lane's slice of the points
    const float ba0 = ba[0], bb0 = bb[0];

    // per-lane weight registers: lane l covers col4 indices l and 64+l
    const float4* Wa4 = reinterpret_cast<const float4*>(Wa);
    const float4* Wb4 = reinterpret_cast<const float4*>(Wb);
    const float4 wa_lo = Wa4[lane], wa_hi = Wa4[64 + lane];
    const float4 wb_lo = Wb4[lane], wb_hi = Wb4[64 + lane];

    const int rowBase = blockIdx.x * 64 + wv * 16;   // 4 groups of 4 rows
    const float4* px = reinterpret_cast<const float4*>(x) + (size_t)rowBase * 128 + lane;

    float4 xv[8];   // single pipeline buffer (32 VGPR)

    // group g occupies float4 indices [g*512, g*512+512) relative to px base
#define LOADG(g)                                                              \
    {                                                                         \
        _Pragma("unroll")                                                     \
        for (int j = 0; j < 8; ++j)                                           \
            xv[j] = px[(size_t)(g) * 512 + j * 64];                           \
    }

#define DOTSG(da, db)                                                         \
    {                                                                         \
        float acca[4], accb[4];                                               \
        _Pragma("unroll")                                                     \
        for (int r = 0; r < 4; ++r) {                                         \
            acca[r] = dot4(xv[2 * r], wa_lo) + dot4(xv[2 * r + 1], wa_hi);    \
            accb[r] = dot4(xv[2 * r], wb_lo) + dot4(xv[2 * r + 1], wb_hi);    \
        }                                                                     \
        _Pragma("unroll")                                                     \
        for (int r = 0; r < 4; ++r) {                                         \
            acca[r] += __shfl_xor(acca[r], 1, 64);                            \
            accb[r] += __shfl_xor(accb[r], 1, 64);                            \
            acca[r] += __shfl_xor(acca[r], 2, 64);                            \
            accb[r] += __shfl_xor(accb[r], 2, 64);                            \
            acca[r] += __shfl_xor(acca[r], 4, 64);                            \
            accb[r] += __shfl_xor(accb[r], 4, 64);                            \
        }                                                                     \
        da = acca[0]; db = accb[0];                                           \
        _Pragma("unroll")                                                     \
        for (int r = 1; r < 4; ++r) {                                         \
            const bool sel = (r4 == r);                                       \
            da = sel ? acca[r] : da;                                          \
            db = sel ? accb[r] : db;                                          \
        }                                                                     \
        da += __shfl_xor(da, 8, 64);  db += __shfl_xor(db, 8, 64);            \
        da += __shfl_xor(da, 16, 64); db += __shfl_xor(db, 16, 64);           \
        da += __shfl_xor(da, 32, 64); db += __shfl_xor(db, 32, 64);           \
        da += ba0; db += bb0;                                                 \
    }

#define QUADG(g, da, db)                                                      \
    {                                                                         \
        const float ua = FAST_EXP2(-fabsf(da) * LOG2E_F);                     \
        const float ub = FAST_EXP2(-fabsf(db) * LOG2E_F);                     \
        const float sa = fmaxf(da, 0.f) + FAST_LOG2(1.f + ua) * LN2_F;        \
        const float sb = fmaxf(db, 0.f) + FAST_LOG2(1.f + ub) * LN2_F;        \
        const float alpha = fminf(fmaxf(1.f + sa, 1.f), 100.f);               \
        const float beta  = fminf(fmaxf(1.f + sb, 1.f), 100.f);               \
        const float am1 = alpha - 1.f, bm1 = beta - 1.f;                      \
        const float den = am1 + bm1;                                          \
        float mm = (den > 0.f) ? am1 / den : 0.5f;                            \
        mm = fminf(fmaxf(mm, 1e-6f), 1.f - 1e-6f);                            \
        const float M2 = am1 * FAST_LOG2(mm) + bm1 * FAST_LOG2(1.f - mm);     \
        float seg[KC];                                                        \
        int base = 0;                                                         \
        _Pragma("unroll")                                                     \
        for (int i = 1; i <= KC; ++i) {                                       \
            const int n = 10 * i;                                             \
            float s = 0.f;                                                    \
            _Pragma("unroll")                                                 \
            for (int t = part; t < n; t += 16) {                              \
                const float2 e = s_tab[base + t];                             \
                s += FAST_EXP2(fmaf(am1, e.x, fmaf(bm1, e.y, -M2)));          \
            }                                                                 \
            seg[i - 1] = s;                                                   \
            base += n;                                                        \
        }                                                                     \
        _Pragma("unroll")                                                     \
        for (int i = 0; i < KC; ++i) {                                        \
            seg[i] += __shfl_xor(seg[i], 4, 64);                              \
            seg[i] += __shfl_xor(seg[i], 8, 64);                              \
            seg[i] += __shfl_xor(seg[i], 16, 64);                             \
            seg[i] += __shfl_xor(seg[i], 32, 64);                             \
        }                                                                     \
        if (part == 0) {                                                      \
            float* orow = out + (size_t)(rowBase + (g) * 4 + r4) * KC;        \
            const float inv_total = 1.f / seg[KC - 1];                        \
            float prev = 0.f;                                                 \
            float2* o2 = reinterpret_cast<float2*>(orow);                     \
            _Pragma("unroll")                                                 \
            for (int j = 0; j < KC; j += 2) {                                 \
                const float p0 = (seg[j]     - prev)   * inv_total;           \
                const float p1 = (seg[j + 1] - seg[j]) * inv_total;           \
                o2[j >> 1] = make_float2(p0, p1);                             \
                prev = seg[j + 1];                                            \
            }                                                                 \
        }                                                                     \
    }

    float da0, db0, da1, db1, da2, db2, da3, db3;
    LOADG(0);
    DOTSG(da0, db0);       // consumes xv; buffer dead afterwards
    LOADG(1);              // in flight under quad(0)
    QUADG(0, da0, db0);
    DOTSG(da1, db1);
    LOADG(2);              // in flight under quad(1)
    QUADG(1, da1, db1);
    DOTSG(da2, db2);
    LOADG(3);              // in flight under quad(2)
    QUADG(2, da2, db2);
    DOTSG(da3, db3);
    QUADG(3, da3, db3);

#undef LOADG
#undef DOTSG
#undef QUADG
}

// ---------------- Fallback: round-1 fused kernel (passed) ------------------
__global__ __launch_bounds__(256, 4) void ub_fused_kernel(
    const float* __restrict__ x, const float* __restrict__ Wa,
    const float* __restrict__ ba, const float* __restrict__ Wb,
    const float* __restrict__ bb, float* __restrict__ out,
    int B, int C, int K)
{
    __shared__ __align__(16) float s_lg[600];
    __shared__ __align__(16) float s_l1g[600];
    __shared__ __align__(16) float s_w[1024];

    const int tid = threadIdx.x;
    for (int c = tid; c < C; c += blockDim.x) {
        s_w[c]     = Wa[c];
        s_w[C + c] = Wb[c];
    }
    {
        int base = 0;
        for (int i = 1; i <= K; ++i) {
            const int n = (int)((double)NPTS_C * ((double)i / (double)K));
            const double start = EPS_C;
            const double stop  = (double)i / (double)K - EPS_C;
            const double step  = (n > 1) ? (stop - start) / (double)(n - 1) : 0.0;
            for (int j = tid; j < n; j += blockDim.x) {
                float g = (j == n - 1) ? (float)stop : (float)(start + step * (double)j);
                s_lg[base + j]  = logf(g);
                s_l1g[base + j] = log1pf(-g);
            }
            base += n;
        }
    }
    __syncthreads();

    const float ba0 = ba[0], bb0 = bb[0];
    const int wave = tid >> 6;
    const int lane = tid & 63;
    const int wavesPerBlock = blockDim.x >> 6;
    const int waveId = blockIdx.x * wavesPerBlock + wave;
    const int nWaves = gridDim.x * wavesPerBlock;

    for (int row = waveId; row < B; row += nWaves) {
        const float* xr = x + (size_t)row * C;
        float da = 0.f, db = 0.f;
        for (int c0 = 0; c0 < C; c0 += 256) {
            const float4 xv = *reinterpret_cast<const float4*>(xr + c0 + 4 * lane);
            const float4 wa = *reinterpret_cast<const float4*>(&s_w[c0 + 4 * lane]);
            const float4 wb = *reinterpret_cast<const float4*>(&s_w[C + c0 + 4 * lane]);
            da += xv.x * wa.x + xv.y * wa.y + xv.z * wa.z + xv.w * wa.w;
            db += xv.x * wb.x + xv.y * wb.y + xv.z * wb.z + xv.w * wb.w;
        }
        da = wave_reduce_sum(da) + ba0;
        db = wave_reduce_sum(db) + bb0;

        const float sa = fmaxf(da, 0.f) + log1pf(expf(-fabsf(da)));
        const float sb = fmaxf(db, 0.f) + log1pf(expf(-fabsf(db)));
        const float alpha = fminf(fmaxf(1.f + sa, 1.f), 100.f);
        const float beta  = fminf(fmaxf(1.f + sb, 1.f), 100.f);
        const float log_norm = lgammaf(alpha) + lgammaf(beta) - lgammaf(alpha + beta);
        const float am1 = alpha - 1.f, bm1 = beta - 1.f;

        float cdf_prev = 0.f, myp = 0.f;
        int base = 0;
        for (int i = 1; i <= K; ++i) {
            const int n = (int)((double)NPTS_C * ((double)i / (double)K));
            float s = 0.f;
            for (int p = lane; p < n; p += 64) {
                const float lp = fmaf(am1, s_lg[base + p],
                                 fmaf(bm1, s_l1g[base + p], -log_norm));
                s += expf(lp);
            }
            const float cdf = wave_reduce_sum(s);
            if (lane == i - 1) myp = cdf - cdf_prev;
            cdf_prev = cdf;
            base += n;
        }
        if (lane < K)
            out[(size_t)row * K + lane] = myp / cdf_prev;
    }
}

extern "C" void kernel_launch(void* const* d_in, const int* in_sizes, int n_in,
                              void* d_out, int out_size, void* d_ws, size_t ws_size,
                              hipStream_t stream) {
    const float* x  = (const float*)d_in[0];
    const float* Wa = (const float*)d_in[1];
    const float* ba = (const float*)d_in[2];
    const float* Wb = (const float*)d_in[3];
    const float* bb = (const float*)d_in[4];
    float* out = (float*)d_out;

    const int C = in_sizes[1];           // 512
    const int B = in_sizes[0] / C;       // 65536
    const int K = out_size / B;          // 10

    const bool fast_ok = (C == 512) && (K == 10) && (B % 64 == 0);

    if (fast_ok) {
        fused512_kernel<<<B / 64, 256, 0, stream>>>(x, Wa, ba, Wb, bb, out);
    } else {
        int nblocks = (B + 3) / 4;
        if (nblocks > 2048) nblocks = 2048;
        ub_fused_kernel<<<nblocks, 256, 0, stream>>>(x, Wa, ba, Wb, bb, out, B, C, K);
    }
}

// Round 16
// 28.131 us; speedup vs baseline: 1.1592x; 1.1592x over previous
//
#include <hip/hip_runtime.h>
#include <math.h>

#define NPTS_C 100
#define EPS_C 1e-8

#if defined(__has_builtin)
# if __has_builtin(__builtin_amdgcn_exp2f)
#  define FAST_EXP2(x) __builtin_amdgcn_exp2f(x)
#  define FAST_LOG2(x) __builtin_amdgcn_logf(x)
# else
#  define FAST_EXP2(x) exp2f(x)
#  define FAST_LOG2(x) log2f(x)
# endif
#else
# define FAST_EXP2(x) exp2f(x)
# define FAST_LOG2(x) log2f(x)
#endif

#define LOG2E_F 1.44269504088896340736f
#define LN2_F   0.69314718055994530942f

__device__ __forceinline__ float dot4(float4 a, float4 b) {
    return a.x * b.x + a.y * b.y + a.z * b.z + a.w * b.w;
}

__device__ __forceinline__ float wave_reduce_sum(float v) {
#pragma unroll
    for (int m = 1; m < 64; m <<= 1)
        v += __shfl_xor(v, m, 64);
    return v;
}

// ---------------- fast path constants (C=512, K=10, NPTS=100) --------------
constexpr int KC   = 10;
constexpr int NTAB = 550;   // sum_{i=1..10} 10*i

// Combines the two proven levers:
//  - R14: contiguous loads (each instr reads 64 consecutive float4 = 1KB),
//  - R9:  high occupancy (small work quantum -> low VGPR -> 6 waves/SIMD).
// Block = 256 threads = 4 waves; each wave owns 4 consecutive rows
// (xv[8] = 32 VGPR burst buffer; peak live ~75 VGPR). Grid = B/16 = 4096.
// 24 waves/CU interleave load bursts and quad phases finely -> memory
// stays fed during quads of other waves.
// Dot reduce: xor1/2 (4-lane group sums of 4 accs) -> select by lane&3 ->
// xor4/8/16/32 => row r's (da,db) in every lane with lane&3==r.
// Quad: 16 lanes/row (part = lane>>2), ~34 pts/lane, reduce xor4/8/16/32.
__global__ __launch_bounds__(256, 6) void fused512_kernel(
    const float* __restrict__ x, const float* __restrict__ Wa,
    const float* __restrict__ ba, const float* __restrict__ Wb,
    const float* __restrict__ bb, float* __restrict__ out)
{
    __shared__ __align__(16) float2 s_tab[NTAB];   // (log2 g, log2(1-g)), fp32 grid

    const int tid = threadIdx.x;

    // row-invariant log2 tables (fp32 grid, matches ref; last point of last
    // segment rounds to 1.0f -> log2f(0) = -inf -> exp2 -> 0)
    {
        int base = 0;
#pragma unroll
        for (int i = 1; i <= KC; ++i) {
            const int n = 10 * i;
            const double start = EPS_C;
            const double stop  = (double)i / (double)KC - EPS_C;
            const double step  = (stop - start) / (double)(n - 1);
            for (int j = tid; j < n; j += 256) {
                const double g = (j == n - 1) ? stop : start + step * (double)j;
                const float g32 = (float)g;
                s_tab[base + j] = make_float2(log2f(g32), log2f(1.0f - g32));
            }
            base += n;
        }
    }
    __syncthreads();

    const int lane = tid & 63;
    const int wv   = tid >> 6;
    const int r4   = lane & 3;    // which of the wave's 4 rows
    const int part = lane >> 2;   // 0..15: this lane's slice of the points
    const float ba0 = ba[0], bb0 = bb[0];

    // per-lane weight registers: lane l covers col4 indices l and 64+l
    const float4* Wa4 = reinterpret_cast<const float4*>(Wa);
    const float4* Wb4 = reinterpret_cast<const float4*>(Wb);
    const float4 wa_lo = Wa4[lane], wa_hi = Wa4[64 + lane];
    const float4 wb_lo = Wb4[lane], wb_hi = Wb4[64 + lane];

    const int row0 = blockIdx.x * 16 + wv * 4;
    const float4* px = reinterpret_cast<const float4*>(x) + (size_t)row0 * 128 + lane;

    // ---- phase 1: 8 contiguous 1KB loads (8KB/wave), burst-issued ----
    float4 xv[8];
#pragma unroll
    for (int j = 0; j < 8; ++j)
        xv[j] = px[j * 64];

    // load instr j covers row j>>1, col4 (j&1)*64 + lane
    float acca[4], accb[4];
#pragma unroll
    for (int r = 0; r < 4; ++r) {
        acca[r] = dot4(xv[2 * r], wa_lo) + dot4(xv[2 * r + 1], wa_hi);
        accb[r] = dot4(xv[2 * r], wb_lo) + dot4(xv[2 * r + 1], wb_hi);
    }

    // ---- reduction: 4-lane group sums (xor1/2), select by r4, xor4..32 ----
#pragma unroll
    for (int r = 0; r < 4; ++r) {
        acca[r] += __shfl_xor(acca[r], 1, 64);
        accb[r] += __shfl_xor(accb[r], 1, 64);
        acca[r] += __shfl_xor(acca[r], 2, 64);
        accb[r] += __shfl_xor(accb[r], 2, 64);
    }
    float da = acca[0], db = accb[0];
#pragma unroll
    for (int r = 1; r < 4; ++r) {
        const bool sel = (r4 == r);
        da = sel ? acca[r] : da;
        db = sel ? accb[r] : db;
    }
    da += __shfl_xor(da, 4, 64);  db += __shfl_xor(db, 4, 64);
    da += __shfl_xor(da, 8, 64);  db += __shfl_xor(db, 8, 64);
    da += __shfl_xor(da, 16, 64); db += __shfl_xor(db, 16, 64);
    da += __shfl_xor(da, 32, 64); db += __shfl_xor(db, 32, 64);
    da += ba0; db += bb0;

    // ---- per-row scalars (16-way redundant; hw exp2/log2 forms) ----
    const float ua = FAST_EXP2(-fabsf(da) * LOG2E_F);
    const float ub = FAST_EXP2(-fabsf(db) * LOG2E_F);
    const float sa = fmaxf(da, 0.f) + FAST_LOG2(1.f + ua) * LN2_F;
    const float sb = fmaxf(db, 0.f) + FAST_LOG2(1.f + ub) * LN2_F;
    const float alpha = fminf(fmaxf(1.f + sa, 1.f), 100.f);
    const float beta  = fminf(fmaxf(1.f + sb, 1.f), 100.f);
    const float am1 = alpha - 1.f, bm1 = beta - 1.f;

    // stabilizer at the beta mode (cancels in normalization; avoids underflow)
    const float den = am1 + bm1;
    float mm = (den > 0.f) ? am1 / den : 0.5f;
    mm = fminf(fmaxf(mm, 1e-6f), 1.f - 1e-6f);
    const float M2 = am1 * FAST_LOG2(mm) + bm1 * FAST_LOG2(1.f - mm);

    // ---- phase 2: quadrature, 16 lanes per row, points strided by 16 ----
    float seg[KC];
    {
        int base = 0;
#pragma unroll
        for (int i = 1; i <= KC; ++i) {
            const int n = 10 * i;
            float s = 0.f;
#pragma unroll
            for (int t = part; t < n; t += 16) {
                const float2 e = s_tab[base + t];
                s += FAST_EXP2(fmaf(am1, e.x, fmaf(bm1, e.y, -M2)));
            }
            seg[i - 1] = s;
            base += n;
        }
    }
#pragma unroll
    for (int i = 0; i < KC; ++i) {
        seg[i] += __shfl_xor(seg[i], 4, 64);
        seg[i] += __shfl_xor(seg[i], 8, 64);
        seg[i] += __shfl_xor(seg[i], 16, 64);
        seg[i] += __shfl_xor(seg[i], 32, 64);
    }

    if (part == 0) {
        float* orow = out + (size_t)(row0 + r4) * KC;
        const float inv_total = 1.f / seg[KC - 1];   // total = cdf_K (telescoping)
        float prev = 0.f;
        float2* o2 = reinterpret_cast<float2*>(orow);  // 40B rows are 8B-aligned
#pragma unroll
        for (int j = 0; j < KC; j += 2) {
            const float p0 = (seg[j]     - prev)   * inv_total;
            const float p1 = (seg[j + 1] - seg[j]) * inv_total;
            o2[j >> 1] = make_float2(p0, p1);
            prev = seg[j + 1];
        }
    }
}

// ---------------- Fallback: round-1 fused kernel (passed) ------------------
__global__ __launch_bounds__(256, 4) void ub_fused_kernel(
    const float* __restrict__ x, const float* __restrict__ Wa,
    const float* __restrict__ ba, const float* __restrict__ Wb,
    const float* __restrict__ bb, float* __restrict__ out,
    int B, int C, int K)
{
    __shared__ __align__(16) float s_lg[600];
    __shared__ __align__(16) float s_l1g[600];
    __shared__ __align__(16) float s_w[1024];

    const int tid = threadIdx.x;
    for (int c = tid; c < C; c += blockDim.x) {
        s_w[c]     = Wa[c];
        s_w[C + c] = Wb[c];
    }
    {
        int base = 0;
        for (int i = 1; i <= K; ++i) {
            const int n = (int)((double)NPTS_C * ((double)i / (double)K));
            const double start = EPS_C;
            const double stop  = (double)i / (double)K - EPS_C;
            const double step  = (n > 1) ? (stop - start) / (double)(n - 1) : 0.0;
            for (int j = tid; j < n; j += blockDim.x) {
                float g = (j == n - 1) ? (float)stop : (float)(start + step * (double)j);
                s_lg[base + j]  = logf(g);
                s_l1g[base + j] = log1pf(-g);
            }
            base += n;
        }
    }
    __syncthreads();

    const float ba0 = ba[0], bb0 = bb[0];
    const int wave = tid >> 6;
    const int lane = tid & 63;
    const int wavesPerBlock = blockDim.x >> 6;
    const int waveId = blockIdx.x * wavesPerBlock + wave;
    const int nWaves = gridDim.x * wavesPerBlock;

    for (int row = waveId; row < B; row += nWaves) {
        const float* xr = x + (size_t)row * C;
        float da = 0.f, db = 0.f;
        for (int c0 = 0; c0 < C; c0 += 256) {
            const float4 xv = *reinterpret_cast<const float4*>(xr + c0 + 4 * lane);
            const float4 wa = *reinterpret_cast<const float4*>(&s_w[c0 + 4 * lane]);
            const float4 wb = *reinterpret_cast<const float4*>(&s_w[C + c0 + 4 * lane]);
            da += xv.x * wa.x + xv.y * wa.y + xv.z * wa.z + xv.w * wa.w;
            db += xv.x * wb.x + xv.y * wb.y + xv.z * wb.z + xv.w * wb.w;
        }
        da = wave_reduce_sum(da) + ba0;
        db = wave_reduce_sum(db) + bb0;

        const float sa = fmaxf(da, 0.f) + log1pf(expf(-fabsf(da)));
        const float sb = fmaxf(db, 0.f) + log1pf(expf(-fabsf(db)));
        const float alpha = fminf(fmaxf(1.f + sa, 1.f), 100.f);
        const float beta  = fminf(fmaxf(1.f + sb, 1.f), 100.f);
        const float log_norm = lgammaf(alpha) + lgammaf(beta) - lgammaf(alpha + beta);
        const float am1 = alpha - 1.f, bm1 = beta - 1.f;

        float cdf_prev = 0.f, myp = 0.f;
        int base = 0;
        for (int i = 1; i <= K; ++i) {
            const int n = (int)((double)NPTS_C * ((double)i / (double)K));
            float s = 0.f;
            for (int p = lane; p < n; p += 64) {
                const float lp = fmaf(am1, s_lg[base + p],
                                 fmaf(bm1, s_l1g[base + p], -log_norm));
                s += expf(lp);
            }
            const float cdf = wave_reduce_sum(s);
            if (lane == i - 1) myp = cdf - cdf_prev;
            cdf_prev = cdf;
            base += n;
        }
        if (lane < K)
            out[(size_t)row * K + lane] = myp / cdf_prev;
    }
}

extern "C" void kernel_launch(void* const* d_in, const int* in_sizes, int n_in,
                              void* d_out, int out_size, void* d_ws, size_t ws_size,
                              hipStream_t stream) {
    const float* x  = (const float*)d_in[0];
    const float* Wa = (const float*)d_in[1];
    const float* ba = (const float*)d_in[2];
    const float* Wb = (const float*)d_in[3];
    const float* bb = (const float*)d_in[4];
    float* out = (float*)d_out;

    const int C = in_sizes[1];           // 512
    const int B = in_sizes[0] / C;       // 65536
    const int K = out_size / B;          // 10

    const bool fast_ok = (C == 512) && (K == 10) && (B % 16 == 0);

    if (fast_ok) {
        fused512_kernel<<<B / 16, 256, 0, stream>>>(x, Wa, ba, Wb, bb, out);
    } else {
        int nblocks = (B + 3) / 4;
        if (nblocks > 2048) nblocks = 2048;
        ub_fused_kernel<<<nblocks, 256, 0, stream>>>(x, Wa, ba, Wb, bb, out, B, C, K);
    }
}